// Round 1
// baseline (247.746 us; speedup 1.0000x reference)
//
#include <hip/hip_runtime.h>
#include <cmath>
#include <cstdint>

// Problem constants (B=2, C=32, Z=4, E=2, N=C*C*Z=4096)
namespace {
constexpr int NPT  = 4096;          // points per (b,e) slice
constexpr int NS   = 4;             // B*E slices
constexpr int NTOT = NS * NPT;      // 16384

// output offsets (in floats), concatenated in reference return order
constexpr int O_PPOS  = 0;                  // [B,E,N,3]
constexpr int O_MASKP = O_PPOS + NTOT * 3;  // 49152
constexpr int O_KEEP  = O_MASKP + NTOT;     // 65536
constexpr int O_TPOS  = O_KEEP + NTOT;      // 81920
constexpr int O_MASKT = O_TPOS + NTOT * 3;  // 131072
constexpr int O_TPT   = O_MASKT + NTOT;     // 147456
constexpr int O_TPP   = O_TPT + NTOT;       // 163840
constexpr int O_TPTN  = O_TPP + NTOT;       // 180224
constexpr int O_TPPN  = O_TPTN + NTOT;      // 196608

// workspace offsets (bytes)
constexpr size_t W_PP4   = 0;               // float4[NTOT] (x,y,z,key) key=valid?conf:-1
constexpr size_t W_TP4   = 262144;          // float4[NTOT] (x,y,z, tvalid?1:-1)
constexpr size_t W_KEEPF = 524288;          // float[NTOT]  keep?1:-1
constexpr size_t W_RESTR = 589824;          // uint[NTOT]
constexpr size_t W_SUPPR = 655360;          // uint[NTOT]
constexpr size_t W_ANYS  = 720896;          // uint[NTOT]
constexpr size_t W_ANYN  = 786432;          // uint[NTOT]
constexpr size_t W_ENCS  = 851968;          // u64[NTOT]
constexpr size_t W_ENCN  = 983040;          // u64[NTOT]
} // namespace

// ---------------------------------------------------------------------------
// K1: elementwise setup + workspace init.
// grid 64x256, one thread per (b,e,n).
__global__ void k_setup(const float4* __restrict__ pred, const float4* __restrict__ tgt,
                        float* __restrict__ out,
                        float4* __restrict__ pp4, float4* __restrict__ tp4,
                        unsigned* __restrict__ restr, unsigned* __restrict__ suppr,
                        unsigned* __restrict__ anys, unsigned* __restrict__ anyn,
                        unsigned long long* __restrict__ encs,
                        unsigned long long* __restrict__ encn) {
#pragma clang fp contract(off)
    int tid = blockIdx.x * 256 + threadIdx.x;   // = s*NPT + n
    int n = tid & (NPT - 1);
    int s = tid >> 12;                          // b*2 + e
    int b = s >> 1, e = s & 1;
    // input flat float index: b*32768 + 8n + 4e + k  -> float4 index b*8192 + 2n + e
    float4 p = pred[b * 8192 + n * 2 + e];
    float4 t = tgt [b * 8192 + n * 2 + e];
    float fx = (float)(n >> 7);
    float fy = (float)((n >> 2) & 31);
    float fz = (float)(n & 3);
    const float lx = 0.78125f, ly = 0.78125f, lz = 0.75f;  // 25/32, 25/32, 3/4 (exact)
    float px = (p.x + fx) * lx, py = (p.y + fy) * ly, pz = (p.z + fz) * lz;
    float tx = (t.x + fx) * lx, ty = (t.y + fy) * ly, tz = (t.z + fz) * lz;
    bool pv = p.w > 0.5f;
    bool tv = t.w > 0.5f;

    out[O_PPOS + tid * 3 + 0] = px;
    out[O_PPOS + tid * 3 + 1] = py;
    out[O_PPOS + tid * 3 + 2] = pz;
    out[O_MASKP + tid] = pv ? 1.0f : 0.0f;
    out[O_TPOS + tid * 3 + 0] = tx;
    out[O_TPOS + tid * 3 + 1] = ty;
    out[O_TPOS + tid * 3 + 2] = tz;
    out[O_MASKT + tid] = tv ? 1.0f : 0.0f;

    pp4[tid] = make_float4(px, py, pz, pv ? p.w : -1.0f);
    tp4[tid] = make_float4(tx, ty, tz, tv ? 1.0f : -1.0f);
    restr[tid] = 0u;
    suppr[tid] = 0u;
    anys[tid]  = 0u;
    anyn[tid]  = 0u;
    encs[tid]  = ~0ull;
    encn[tid]  = ~0ull;
}

// ---------------------------------------------------------------------------
// K2: restrain[j] = #{ i : valid_i, dist(i,j)<d, prec(i,j) }
// prec(i,j) = (c_i > c_j) || (c_i == c_j && i < j)   [stable desc sort order]
// grid 512 blocks: s(4) x jtile(16) x iquarter(8); block 256 threads (one j each).
__global__ void __launch_bounds__(256) k_restrain(const float4* __restrict__ pp4,
                                                  unsigned* __restrict__ restr,
                                                  float s0, float s1) {
#pragma clang fp contract(off)
    __shared__ float4 tile[512];
    int bid = blockIdx.x;
    int iq = bid & 7;
    int jt = (bid >> 3) & 15;
    int s  = bid >> 7;
    int j  = jt * 256 + threadIdx.x;
    float se = (s & 1) ? s1 : s0;
    int base = s * NPT;
    int i0 = iq * 512;
    for (int t = threadIdx.x; t < 512; t += 256) tile[t] = pp4[base + i0 + t];
    __syncthreads();
    float4 pj = pp4[base + j];
    if (pj.w < 0.0f) return;   // invalid j: reference restrain column unused
    unsigned cnt = 0;
#pragma unroll 8
    for (int t = 0; t < 512; ++t) {
        float4 pi = tile[t];
        float dx = pj.x - pi.x, dy = pj.y - pi.y, dz = pj.z - pi.z;
        float d2 = dx * dx + dy * dy;
        d2 = d2 + dz * dz;
        int ig = i0 + t;
        bool prec = (pi.w > pj.w) || ((pi.w == pj.w) && (ig < j));
        if ((pi.w > 0.0f) && (d2 < se) && prec) cnt++;
    }
    if (cnt) atomicAdd(&restr[base + j], cnt);
}

// ---------------------------------------------------------------------------
// K3: suppr[j] = exists i : valid_i, restrain[i]==0, dist<d, prec(i,j)
__global__ void __launch_bounds__(256) k_suppress(const float4* __restrict__ pp4,
                                                  const unsigned* __restrict__ restr,
                                                  unsigned* __restrict__ suppr,
                                                  float s0, float s1) {
#pragma clang fp contract(off)
    __shared__ float4 tile[512];
    __shared__ float flg[512];
    int bid = blockIdx.x;
    int iq = bid & 7;
    int jt = (bid >> 3) & 15;
    int s  = bid >> 7;
    int j  = jt * 256 + threadIdx.x;
    float se = (s & 1) ? s1 : s0;
    int base = s * NPT;
    int i0 = iq * 512;
    for (int t = threadIdx.x; t < 512; t += 256) {
        float4 v = pp4[base + i0 + t];
        tile[t] = v;
        flg[t] = (v.w > 0.0f && restr[base + i0 + t] == 0u) ? 1.0f : 0.0f;
    }
    __syncthreads();
    float4 pj = pp4[base + j];
    if (pj.w < 0.0f) return;
    bool any = false;
#pragma unroll 8
    for (int t = 0; t < 512; ++t) {
        float4 pi = tile[t];
        float dx = pj.x - pi.x, dy = pj.y - pi.y, dz = pj.z - pi.z;
        float d2 = dx * dx + dy * dy;
        d2 = d2 + dz * dz;
        int ig = i0 + t;
        bool prec = (pi.w > pj.w) || ((pi.w == pj.w) && (ig < j));
        any = any || ((flg[t] > 0.0f) && (d2 < se) && prec);
    }
    if (any) atomicOr(&suppr[base + j], 1u);
}

// ---------------------------------------------------------------------------
// K4: keep = valid && !suppressed ; write output + keepf flag for match pass
__global__ void k_keep(const float4* __restrict__ pp4, const unsigned* __restrict__ suppr,
                       float* __restrict__ out, float* __restrict__ keepf) {
    int tid = blockIdx.x * 256 + threadIdx.x;
    bool keep = (pp4[tid].w > 0.0f) && (suppr[tid] == 0u);
    out[O_KEEP + tid] = keep ? 1.0f : 0.0f;
    keepf[tid] = keep ? 1.0f : -1.0f;
}

// ---------------------------------------------------------------------------
// K5: TP match, both variants (p_valid = mask_p, and p_valid = keep).
// Per t-row: any(dist<d) and argmin over sqrtf(d2) (first occurrence).
// Cross-block combine: atomicMin on (dist_bits<<32 | idx).
__global__ void __launch_bounds__(256) k_match(const float4* __restrict__ pp4,
                                               const float4* __restrict__ tp4,
                                               const float* __restrict__ keepf,
                                               unsigned long long* __restrict__ encs,
                                               unsigned long long* __restrict__ encn,
                                               unsigned* __restrict__ anys,
                                               unsigned* __restrict__ anyn,
                                               float s0, float s1) {
#pragma clang fp contract(off)
    __shared__ float4 tile[512];
    __shared__ float kf[512];
    int bid = blockIdx.x;
    int iq = bid & 7;
    int jt = (bid >> 3) & 15;
    int s  = bid >> 7;
    int j  = jt * 256 + threadIdx.x;
    float se = (s & 1) ? s1 : s0;
    int base = s * NPT;
    int i0 = iq * 512;
    for (int t = threadIdx.x; t < 512; t += 256) {
        tile[t] = pp4[base + i0 + t];
        kf[t] = keepf[base + i0 + t];
    }
    __syncthreads();
    float4 tj = tp4[base + j];
    if (tj.w < 0.0f) return;   // invalid t: row is all-inf -> mask 0, idx 0 (from init)
    float bs = __builtin_inff(), bn = __builtin_inff();
    int is_ = 0, in_ = 0;
    bool as_ = false, an_ = false;
#pragma unroll 8
    for (int t = 0; t < 512; ++t) {
        float4 pi = tile[t];
        float dx = tj.x - pi.x, dy = tj.y - pi.y, dz = tj.z - pi.z;
        float d2 = dx * dx + dy * dy;
        d2 = d2 + dz * dz;
        float dist = sqrtf(d2);       // correctly-rounded; argmin on dist matches numpy
        int ig = i0 + t;
        if (pi.w > 0.0f) {
            if (d2 < se) as_ = true;
            if (dist < bs) { bs = dist; is_ = ig; }
        }
        if (kf[t] > 0.0f) {
            if (d2 < se) an_ = true;
            if (dist < bn) { bn = dist; in_ = ig; }
        }
    }
    unsigned long long es = ((unsigned long long)__float_as_uint(bs) << 32) | (unsigned)is_;
    unsigned long long en = ((unsigned long long)__float_as_uint(bn) << 32) | (unsigned)in_;
    atomicMin(&encs[base + j], es);
    atomicMin(&encn[base + j], en);
    if (as_) atomicOr(&anys[base + j], 1u);
    if (an_) atomicOr(&anyn[base + j], 1u);
}

// ---------------------------------------------------------------------------
// K6: decode match results to outputs
__global__ void k_finmatch(const float4* __restrict__ tp4,
                           const unsigned long long* __restrict__ encs,
                           const unsigned long long* __restrict__ encn,
                           const unsigned* __restrict__ anys,
                           const unsigned* __restrict__ anyn,
                           float* __restrict__ out) {
    int tid = blockIdx.x * 256 + threadIdx.x;
    bool tv = tp4[tid].w > 0.0f;
    unsigned is_ = tv ? (unsigned)(encs[tid] & 0xffffffffull) : 0u;
    unsigned in_ = tv ? (unsigned)(encn[tid] & 0xffffffffull) : 0u;
    out[O_TPT  + tid] = (tv && anys[tid]) ? 1.0f : 0.0f;
    out[O_TPP  + tid] = (float)is_;
    out[O_TPTN + tid] = (tv && anyn[tid]) ? 1.0f : 0.0f;
    out[O_TPPN + tid] = (float)in_;
}

// ---------------------------------------------------------------------------
// host: exact squared-threshold boundary: smallest f with sqrtf(f) >= t,
// so that (d2 < f) <=> (sqrtf(d2) < t) bit-exactly.
static float sq_boundary(float t) {
    float f = (float)((double)t * (double)t);
    while (sqrtf(f) >= t) f = nextafterf(f, 0.0f);
    while (sqrtf(f) < t)  f = nextafterf(f, __builtin_inff());
    return f;
}

extern "C" void kernel_launch(void* const* d_in, const int* in_sizes, int n_in,
                              void* d_out, int out_size, void* d_ws, size_t ws_size,
                              hipStream_t stream) {
    (void)in_sizes; (void)n_in; (void)out_size; (void)ws_size;
    const float4* pred = (const float4*)d_in[0];
    const float4* tgt  = (const float4*)d_in[1];
    float* out = (float*)d_out;
    char* ws = (char*)d_ws;

    float4* pp4   = (float4*)(ws + W_PP4);
    float4* tp4   = (float4*)(ws + W_TP4);
    float*  keepf = (float*)(ws + W_KEEPF);
    unsigned* restr = (unsigned*)(ws + W_RESTR);
    unsigned* suppr = (unsigned*)(ws + W_SUPPR);
    unsigned* anys  = (unsigned*)(ws + W_ANYS);
    unsigned* anyn  = (unsigned*)(ws + W_ANYN);
    unsigned long long* encs = (unsigned long long*)(ws + W_ENCS);
    unsigned long long* encn = (unsigned long long*)(ws + W_ENCN);

    float s0 = sq_boundary(0.74f);    // ELE_D[0]
    float s1 = sq_boundary(0.528f);   // ELE_D[1]

    k_setup<<<dim3(64), dim3(256), 0, stream>>>(pred, tgt, out, pp4, tp4,
                                                restr, suppr, anys, anyn, encs, encn);
    k_restrain<<<dim3(512), dim3(256), 0, stream>>>(pp4, restr, s0, s1);
    k_suppress<<<dim3(512), dim3(256), 0, stream>>>(pp4, restr, suppr, s0, s1);
    k_keep<<<dim3(64), dim3(256), 0, stream>>>(pp4, suppr, out, keepf);
    k_match<<<dim3(512), dim3(256), 0, stream>>>(pp4, tp4, keepf, encs, encn,
                                                 anys, anyn, s0, s1);
    k_finmatch<<<dim3(64), dim3(256), 0, stream>>>(tp4, encs, encn, anys, anyn, out);
}

// Round 2
// 109.905 us; speedup vs baseline: 2.2542x; 2.2542x over previous
//
#include <hip/hip_runtime.h>
#include <cmath>
#include <cstdint>

// Problem constants (B=2, C=32, Z=4, E=2, N=C*C*Z=4096)
// Lattice structure: one candidate point per cell, cell pitch (0.78125, 0.78125, 0.75),
// point offsets in [0,1) of a cell => dist < ele_d (0.74/0.528) pairs are confined to
// 3x3x3 adjacent cells; any point outside the 5x5x5 neighborhood is >= 1.5 away.
namespace {
constexpr int NPT  = 4096;          // points per (b,e) slice
constexpr int NS   = 4;             // B*E slices
constexpr int NTOT = NS * NPT;      // 16384

// output offsets (floats), reference return order
constexpr int O_PPOS  = 0;
constexpr int O_MASKP = O_PPOS + NTOT * 3;  // 49152
constexpr int O_KEEP  = O_MASKP + NTOT;     // 65536
constexpr int O_TPOS  = O_KEEP + NTOT;      // 81920
constexpr int O_MASKT = O_TPOS + NTOT * 3;  // 131072
constexpr int O_TPT   = O_MASKT + NTOT;     // 147456
constexpr int O_TPP   = O_TPT + NTOT;       // 163840
constexpr int O_TPTN  = O_TPP + NTOT;       // 180224
constexpr int O_TPPN  = O_TPTN + NTOT;      // 196608

// workspace offsets (bytes)
constexpr size_t W_PP4   = 0;        // float4[NTOT] (x,y,z, valid?conf:-1)
constexpr size_t W_TP4   = 262144;   // float4[NTOT] (x,y,z, tvalid?1:-1)
constexpr size_t W_KEEPF = 524288;   // float[NTOT]  keep?1:-1
constexpr size_t W_RESTR = 589824;   // uint[NTOT]
constexpr size_t W_ENCS  = 655360;   // u64[NTOT]
constexpr size_t W_ENCN  = 786432;   // u64[NTOT]
constexpr size_t W_LIST  = 917504;   // uint[NTOT] fallback rows
constexpr size_t W_CNT   = 983040;   // uint

// Outside the 5x5x5 neighborhood true dist >= 1.5; computed dist >= 1.5*(1-4e-7).
// Accept neighborhood argmin iff best < GUARD (strict => no outside point can tie).
constexpr float GUARD = 1.4999f;
} // namespace

// ---------------------------------------------------------------------------
// K1: elementwise setup + workspace init (64 blocks x 256).
__global__ void k_setup(const float4* __restrict__ pred, const float4* __restrict__ tgt,
                        float* __restrict__ out,
                        float4* __restrict__ pp4, float4* __restrict__ tp4,
                        unsigned long long* __restrict__ encs,
                        unsigned long long* __restrict__ encn,
                        unsigned* __restrict__ cnt) {
#pragma clang fp contract(off)
    int tid = blockIdx.x * 256 + threadIdx.x;   // = s*NPT + n
    int n = tid & (NPT - 1);
    int s = tid >> 12;                          // b*2 + e
    int b = s >> 1, e = s & 1;
    float4 p = pred[b * 8192 + n * 2 + e];
    float4 t = tgt [b * 8192 + n * 2 + e];
    float fx = (float)(n >> 7);
    float fy = (float)((n >> 2) & 31);
    float fz = (float)(n & 3);
    const float lx = 0.78125f, ly = 0.78125f, lz = 0.75f;
    float px = (p.x + fx) * lx, py = (p.y + fy) * ly, pz = (p.z + fz) * lz;
    float tx = (t.x + fx) * lx, ty = (t.y + fy) * ly, tz = (t.z + fz) * lz;
    bool pv = p.w > 0.5f;
    bool tv = t.w > 0.5f;

    out[O_PPOS + tid * 3 + 0] = px;
    out[O_PPOS + tid * 3 + 1] = py;
    out[O_PPOS + tid * 3 + 2] = pz;
    out[O_MASKP + tid] = pv ? 1.0f : 0.0f;
    out[O_TPOS + tid * 3 + 0] = tx;
    out[O_TPOS + tid * 3 + 1] = ty;
    out[O_TPOS + tid * 3 + 2] = tz;
    out[O_MASKT + tid] = tv ? 1.0f : 0.0f;

    pp4[tid] = make_float4(px, py, pz, pv ? p.w : -1.0f);
    tp4[tid] = make_float4(tx, ty, tz, tv ? 1.0f : -1.0f);
    encs[tid] = ~0ull;
    encn[tid] = ~0ull;
    if (tid == 0) *cnt = 0u;
}

// ---------------------------------------------------------------------------
// K2: restrain[j] over the exact 27-cell neighborhood.
// prec(i,j) = (c_i > c_j) || (c_i == c_j && i < j)  [stable desc-sort order]
__global__ void k_restrain27(const float4* __restrict__ pp4,
                             unsigned* __restrict__ restr, float s0, float s1) {
#pragma clang fp contract(off)
    int tid = blockIdx.x * 256 + threadIdx.x;
    int n = tid & (NPT - 1);
    int s = tid >> 12;
    int base = s * NPT;
    float se = (s & 1) ? s1 : s0;
    float4 pj = pp4[tid];
    unsigned c = 0;
    if (pj.w > 0.0f) {
        int gx = n >> 7, gy = (n >> 2) & 31, gz = n & 3;
        for (int dx = -1; dx <= 1; ++dx) {
            int nx = gx + dx; if ((unsigned)nx > 31u) continue;
            for (int dy = -1; dy <= 1; ++dy) {
                int ny = gy + dy; if ((unsigned)ny > 31u) continue;
                for (int dz = -1; dz <= 1; ++dz) {
                    int nz = gz + dz; if ((unsigned)nz > 3u) continue;
                    int ni = nx * 128 + ny * 4 + nz;   // self (ni==n): prec false, harmless
                    float4 pi = pp4[base + ni];
                    float ddx = pj.x - pi.x, ddy = pj.y - pi.y, ddz = pj.z - pi.z;
                    float d2 = ddx * ddx + ddy * ddy;
                    d2 = d2 + ddz * ddz;
                    bool prec = (pi.w > pj.w) || ((pi.w == pj.w) && (ni < n));
                    if ((pi.w > 0.0f) && (d2 < se) && prec) c++;
                }
            }
        }
    }
    restr[tid] = c;
}

// ---------------------------------------------------------------------------
// K3: suppressed[j] = exists nbr i: valid_i, restrain[i]==0, dist<d, prec(i,j).
// Fuses keep-finalize: keep = valid && !suppressed.
__global__ void k_suppress27(const float4* __restrict__ pp4,
                             const unsigned* __restrict__ restr,
                             float* __restrict__ out, float* __restrict__ keepf,
                             float s0, float s1) {
#pragma clang fp contract(off)
    int tid = blockIdx.x * 256 + threadIdx.x;
    int n = tid & (NPT - 1);
    int s = tid >> 12;
    int base = s * NPT;
    float se = (s & 1) ? s1 : s0;
    float4 pj = pp4[tid];
    bool sup = false;
    if (pj.w > 0.0f) {
        int gx = n >> 7, gy = (n >> 2) & 31, gz = n & 3;
        for (int dx = -1; dx <= 1; ++dx) {
            int nx = gx + dx; if ((unsigned)nx > 31u) continue;
            for (int dy = -1; dy <= 1; ++dy) {
                int ny = gy + dy; if ((unsigned)ny > 31u) continue;
                for (int dz = -1; dz <= 1; ++dz) {
                    int nz = gz + dz; if ((unsigned)nz > 3u) continue;
                    int ni = nx * 128 + ny * 4 + nz;
                    float4 pi = pp4[base + ni];
                    float ddx = pj.x - pi.x, ddy = pj.y - pi.y, ddz = pj.z - pi.z;
                    float d2 = ddx * ddx + ddy * ddy;
                    d2 = d2 + ddz * ddz;
                    bool prec = (pi.w > pj.w) || ((pi.w == pj.w) && (ni < n));
                    bool flg = (pi.w > 0.0f) && (restr[base + ni] == 0u);
                    sup = sup || (flg && (d2 < se) && prec);
                }
            }
        }
    }
    bool keep = (pj.w > 0.0f) && !sup;
    out[O_KEEP + tid] = keep ? 1.0f : 0.0f;
    keepf[tid] = keep ? 1.0f : -1.0f;
}

// ---------------------------------------------------------------------------
// K4: match phase 1 — 5x5x5 neighborhood argmin (both variants) + exact any-masks.
// any(dist<ele_d) is exactly 27-cell-local, and d2<se is automatically false for
// the outer shell, so evaluating it over the 125 set is exact.
// Accept argmin iff best dist < GUARD; else append row to fallback list.
__global__ void k_match_p1(const float4* __restrict__ pp4, const float4* __restrict__ tp4,
                           const float* __restrict__ keepf,
                           unsigned long long* __restrict__ encs,
                           unsigned long long* __restrict__ encn,
                           float* __restrict__ out,
                           unsigned* __restrict__ list, unsigned* __restrict__ cnt,
                           float s0, float s1) {
#pragma clang fp contract(off)
    int tid = blockIdx.x * 256 + threadIdx.x;
    int n = tid & (NPT - 1);
    int s = tid >> 12;
    int base = s * NPT;
    float se = (s & 1) ? s1 : s0;
    float4 tj = tp4[tid];
    if (tj.w < 0.0f) {   // invalid t: masks 0; enc stays ~0 -> idx 0 in finalize
        out[O_TPT + tid] = 0.0f;
        out[O_TPTN + tid] = 0.0f;
        return;
    }
    int gx = n >> 7, gy = (n >> 2) & 31, gz = n & 3;
    unsigned long long bs = ~0ull, bn = ~0ull;
    bool as_ = false, an_ = false;
    for (int dx = -2; dx <= 2; ++dx) {
        int nx = gx + dx; if ((unsigned)nx > 31u) continue;
        for (int dy = -2; dy <= 2; ++dy) {
            int ny = gy + dy; if ((unsigned)ny > 31u) continue;
            for (int dz = -2; dz <= 2; ++dz) {
                int nz = gz + dz; if ((unsigned)nz > 3u) continue;
                int ni = nx * 128 + ny * 4 + nz;
                float4 pi = pp4[base + ni];
                float kf = keepf[base + ni];
                float ddx = tj.x - pi.x, ddy = tj.y - pi.y, ddz = tj.z - pi.z;
                float d2 = ddx * ddx + ddy * ddy;
                d2 = d2 + ddz * ddz;
                float dist = sqrtf(d2);
                unsigned long long enc =
                    ((unsigned long long)__float_as_uint(dist) << 32) | (unsigned)ni;
                if (pi.w > 0.0f) { if (enc < bs) bs = enc; if (d2 < se) as_ = true; }
                if (kf > 0.0f)   { if (enc < bn) bn = enc; if (d2 < se) an_ = true; }
            }
        }
    }
    out[O_TPT + tid]  = as_ ? 1.0f : 0.0f;
    out[O_TPTN + tid] = an_ ? 1.0f : 0.0f;
    // empty best -> high word 0xFFFFFFFF = NaN -> compare false -> fallback
    bool acc_s = __uint_as_float((unsigned)(bs >> 32)) < GUARD;
    bool acc_n = __uint_as_float((unsigned)(bn >> 32)) < GUARD;
    if (acc_s) encs[tid] = bs;
    if (acc_n) encn[tid] = bn;
    if (!acc_s || !acc_n) {
        unsigned p = atomicAdd(cnt, 1u);
        list[p] = (unsigned)tid;
    }
}

// ---------------------------------------------------------------------------
// K5: match phase 2 — exact full-row scan for fallback rows. One block per row
// (strided over the list); block reduction; direct store (one block owns a row).
__global__ void __launch_bounds__(256) k_match_p2(const float4* __restrict__ pp4,
                                                  const float4* __restrict__ tp4,
                                                  const float* __restrict__ keepf,
                                                  const unsigned* __restrict__ list,
                                                  const unsigned* __restrict__ cnt,
                                                  unsigned long long* __restrict__ encs,
                                                  unsigned long long* __restrict__ encn) {
#pragma clang fp contract(off)
    __shared__ unsigned long long red_s[4], red_n[4];
    unsigned C = *cnt;
    for (unsigned r = blockIdx.x; r < C; r += gridDim.x) {
        int j = (int)list[r];
        int base = (j >> 12) * NPT;
        float4 tj = tp4[j];
        unsigned long long bs = ~0ull, bn = ~0ull;
        for (int k = 0; k < 16; ++k) {
            int ni = k * 256 + (int)threadIdx.x;      // coalesced
            float4 pi = pp4[base + ni];
            float kf = keepf[base + ni];
            float ddx = tj.x - pi.x, ddy = tj.y - pi.y, ddz = tj.z - pi.z;
            float d2 = ddx * ddx + ddy * ddy;
            d2 = d2 + ddz * ddz;
            float dist = sqrtf(d2);
            unsigned long long enc =
                ((unsigned long long)__float_as_uint(dist) << 32) | (unsigned)ni;
            if (pi.w > 0.0f && enc < bs) bs = enc;
            if (kf > 0.0f && enc < bn) bn = enc;
        }
        for (int off = 32; off; off >>= 1) {
            unsigned long long o1 = __shfl_down(bs, off);
            unsigned long long o2 = __shfl_down(bn, off);
            if (o1 < bs) bs = o1;
            if (o2 < bn) bn = o2;
        }
        int wid = (int)(threadIdx.x >> 6);
        if ((threadIdx.x & 63) == 0) { red_s[wid] = bs; red_n[wid] = bn; }
        __syncthreads();
        if (threadIdx.x == 0) {
            for (int w = 1; w < 4; ++w) {
                if (red_s[w] < bs) bs = red_s[w];
                if (red_n[w] < bn) bn = red_n[w];
            }
            encs[j] = bs;   // full-scan result == p1's accepted result when both exist
            encn[j] = bn;
        }
        __syncthreads();   // protect red_* before next row
    }
}

// ---------------------------------------------------------------------------
// K6: decode argmin indices.
__global__ void k_finmatch(const float4* __restrict__ tp4,
                           const unsigned long long* __restrict__ encs,
                           const unsigned long long* __restrict__ encn,
                           float* __restrict__ out) {
    int tid = blockIdx.x * 256 + threadIdx.x;
    bool tv = tp4[tid].w > 0.0f;
    unsigned long long es = encs[tid], en = encn[tid];
    unsigned is_ = (tv && es != ~0ull) ? (unsigned)(es & 0xffffffffull) : 0u;
    unsigned in_ = (tv && en != ~0ull) ? (unsigned)(en & 0xffffffffull) : 0u;
    out[O_TPP  + tid] = (float)is_;
    out[O_TPPN + tid] = (float)in_;
}

// ---------------------------------------------------------------------------
// host: smallest f with sqrtf(f) >= t, so (d2 < f) <=> (sqrtf(d2) < t) bit-exactly.
static float sq_boundary(float t) {
    float f = (float)((double)t * (double)t);
    while (sqrtf(f) >= t) f = nextafterf(f, 0.0f);
    while (sqrtf(f) < t)  f = nextafterf(f, __builtin_inff());
    return f;
}

extern "C" void kernel_launch(void* const* d_in, const int* in_sizes, int n_in,
                              void* d_out, int out_size, void* d_ws, size_t ws_size,
                              hipStream_t stream) {
    (void)in_sizes; (void)n_in; (void)out_size; (void)ws_size;
    const float4* pred = (const float4*)d_in[0];
    const float4* tgt  = (const float4*)d_in[1];
    float* out = (float*)d_out;
    char* ws = (char*)d_ws;

    float4* pp4   = (float4*)(ws + W_PP4);
    float4* tp4   = (float4*)(ws + W_TP4);
    float*  keepf = (float*)(ws + W_KEEPF);
    unsigned* restr = (unsigned*)(ws + W_RESTR);
    unsigned long long* encs = (unsigned long long*)(ws + W_ENCS);
    unsigned long long* encn = (unsigned long long*)(ws + W_ENCN);
    unsigned* list = (unsigned*)(ws + W_LIST);
    unsigned* cnt  = (unsigned*)(ws + W_CNT);

    float s0 = sq_boundary(0.74f);    // ELE_D[0]
    float s1 = sq_boundary(0.528f);   // ELE_D[1]

    k_setup<<<dim3(64), dim3(256), 0, stream>>>(pred, tgt, out, pp4, tp4, encs, encn, cnt);
    k_restrain27<<<dim3(64), dim3(256), 0, stream>>>(pp4, restr, s0, s1);
    k_suppress27<<<dim3(64), dim3(256), 0, stream>>>(pp4, restr, out, keepf, s0, s1);
    k_match_p1<<<dim3(64), dim3(256), 0, stream>>>(pp4, tp4, keepf, encs, encn, out,
                                                   list, cnt, s0, s1);
    k_match_p2<<<dim3(256), dim3(256), 0, stream>>>(pp4, tp4, keepf, list, cnt, encs, encn);
    k_finmatch<<<dim3(64), dim3(256), 0, stream>>>(tp4, encs, encn, out);
}

// Round 3
// 78.687 us; speedup vs baseline: 3.1485x; 1.3967x over previous
//
#include <hip/hip_runtime.h>
#include <cmath>
#include <cstdint>

// Problem: B=2, C=32, Z=4, E=2, N=4096. One candidate point per lattice cell,
// cell pitch (0.78125, 0.78125, 0.75); offsets in [0,1) cell units.
// => dist < ele_d (0.74 / 0.528) pairs confined to 3x3x3 cells (d2 for any
//    |dcell|inf>=2 pair is >= 0.61 >> se even with fp rounding).
// => any point outside the xy +-2 window is >= 1.5625*(1-eps) away: a
//    neighborhood argmin < GUARD=1.4999 is provably the global argmin.
namespace {
constexpr int NPT  = 4096;
constexpr int NTOT = 16384;

// output offsets (floats), reference return order
constexpr int O_PPOS  = 0;
constexpr int O_MASKP = 49152;
constexpr int O_KEEP  = 65536;
constexpr int O_TPOS  = 81920;
constexpr int O_MASKT = 131072;
constexpr int O_TPT   = 147456;
constexpr int O_TPP   = 163840;
constexpr int O_TPTN  = 180224;
constexpr int O_TPPN  = 196608;

// workspace offsets (bytes)
constexpr size_t W_RESTR = 0;       // uchar[16384]
constexpr size_t W_KEEP  = 16384;   // uchar[16384]
constexpr size_t W_CNT   = 32768;   // uint
constexpr size_t W_LIST  = 33024;   // uint[16384]

constexpr float GUARD = 1.4999f;
} // namespace

__device__ __forceinline__ unsigned long long shfl_xor_u64(unsigned long long v, int m) {
    unsigned lo = (unsigned)v, hi = (unsigned)(v >> 32);
    lo = __shfl_xor(lo, m); hi = __shfl_xor(hi, m);
    return ((unsigned long long)hi << 32) | lo;
}
__device__ __forceinline__ unsigned long long shfl_down_u64(unsigned long long v, int m) {
    unsigned lo = (unsigned)v, hi = (unsigned)(v >> 32);
    lo = __shfl_down(lo, m); hi = __shfl_down(hi, m);
    return ((unsigned long long)hi << 32) | lo;
}

// position from raw input + cell index — bit-identical everywhere (contract off,
// lattice constants 25/32 and 3/4 are exactly representable)
__device__ __forceinline__ float3 cellpos(float4 p, int n) {
#pragma clang fp contract(off)
    float fx = (float)(n >> 7), fy = (float)((n >> 2) & 31), fz = (float)(n & 3);
    float3 r;
    r.x = (p.x + fx) * 0.78125f;
    r.y = (p.y + fy) * 0.78125f;
    r.z = (p.z + fz) * 0.75f;
    return r;
}
__device__ __forceinline__ float dist2(float3 a, float3 b) {
#pragma clang fp contract(off)
    float dx = a.x - b.x, dy = a.y - b.y, dz = a.z - b.z;
    float d2 = dx * dx + dy * dy;
    return d2 + dz * dz;   // numpy sum order: (x+y)+z
}

// ---------------------------------------------------------------------------
// K1: restrain counts (2 threads/row) + p_pos/mask_p outputs + cnt init.
// prec(i,j) = (c_i > c_j) || (c_i == c_j && i < j)   [stable desc-sort order]
__global__ void __launch_bounds__(256) k_restrain(const float4* __restrict__ pred,
                                                  float* __restrict__ out,
                                                  unsigned char* __restrict__ restru,
                                                  unsigned* __restrict__ cnt,
                                                  float s0, float s1) {
#pragma clang fp contract(off)
    int tid = blockIdx.x * 256 + threadIdx.x;
    if (tid == 0) *cnt = 0u;
    int row = tid >> 1, h = tid & 1;
    int n = row & (NPT - 1), s = row >> 12, b = s >> 1, e = s & 1;
    int base4 = b * 8192 + e;
    float se = (s & 1) ? s1 : s0;
    float4 p = pred[base4 + n * 2];
    float3 pj = cellpos(p, n);
    bool valid = p.w > 0.5f;
    if (h == 0) {
        out[O_PPOS + row * 3 + 0] = pj.x;
        out[O_PPOS + row * 3 + 1] = pj.y;
        out[O_PPOS + row * 3 + 2] = pj.z;
        out[O_MASKP + row] = valid ? 1.0f : 0.0f;
    }
    unsigned c = 0;
    if (valid) {
        int gx = n >> 7, gy = (n >> 2) & 31;
        for (int qq = 0; qq < 5; ++qq) {
            int q = qq * 2 + h;                  // h=0: {0,2,4,6,8}, h=1: {1,3,5,7}
            if (q > 8) continue;
            int nx = gx + q / 3 - 1, ny = gy + q % 3 - 1;
            if ((unsigned)nx > 31u || (unsigned)ny > 31u) continue;
            int nb = nx * 128 + ny * 4;
#pragma unroll
            for (int nz = 0; nz < 4; ++nz) {     // full z column: exact superset
                int ni = nb + nz;
                float4 pi = pred[base4 + ni * 2];
                float3 qi = cellpos(pi, ni);
                float d2 = dist2(pj, qi);
                bool prec = (pi.w > p.w) || ((pi.w == p.w) && (ni < n));
                if ((pi.w > 0.5f) && (d2 < se) && prec) c++;
            }
        }
    }
    c += __shfl_xor(c, 1);
    if (h == 0) restru[row] = (unsigned char)c;
}

// ---------------------------------------------------------------------------
// K2: suppression + keep output (2 threads/row).
__global__ void __launch_bounds__(256) k_suppress(const float4* __restrict__ pred,
                                                  const unsigned char* __restrict__ restru,
                                                  float* __restrict__ out,
                                                  unsigned char* __restrict__ keepu,
                                                  float s0, float s1) {
#pragma clang fp contract(off)
    int tid = blockIdx.x * 256 + threadIdx.x;
    int row = tid >> 1, h = tid & 1;
    int n = row & (NPT - 1), s = row >> 12, b = s >> 1, e = s & 1;
    int base4 = b * 8192 + e, srow = s * NPT;
    float se = (s & 1) ? s1 : s0;
    float4 p = pred[base4 + n * 2];
    float3 pj = cellpos(p, n);
    bool valid = p.w > 0.5f;
    unsigned any = 0;
    if (valid) {
        int gx = n >> 7, gy = (n >> 2) & 31;
        for (int qq = 0; qq < 5; ++qq) {
            int q = qq * 2 + h;
            if (q > 8) continue;
            int nx = gx + q / 3 - 1, ny = gy + q % 3 - 1;
            if ((unsigned)nx > 31u || (unsigned)ny > 31u) continue;
            int nb = nx * 128 + ny * 4;
#pragma unroll
            for (int nz = 0; nz < 4; ++nz) {
                int ni = nb + nz;
                float4 pi = pred[base4 + ni * 2];
                float3 qi = cellpos(pi, ni);
                float d2 = dist2(pj, qi);
                bool prec = (pi.w > p.w) || ((pi.w == p.w) && (ni < n));
                bool flg = (pi.w > 0.5f) && (restru[srow + ni] == 0);
                if (flg && (d2 < se) && prec) any = 1u;
            }
        }
    }
    any |= __shfl_xor(any, 1);
    if (h == 0) {
        bool keep = valid && !any;
        out[O_KEEP + row] = keep ? 1.0f : 0.0f;
        keepu[row] = keep ? 1 : 0;
    }
}

// ---------------------------------------------------------------------------
// K3: match phase 1 (4 threads/row): 5x5 xy window x full z, both variants,
// exact any-masks, direct output writes for accepted rows, fallback append.
__global__ void __launch_bounds__(256) k_match1(const float4* __restrict__ pred,
                                                const float4* __restrict__ tgt,
                                                const unsigned char* __restrict__ keepu,
                                                float* __restrict__ out,
                                                unsigned* __restrict__ list,
                                                unsigned* __restrict__ cnt,
                                                float s0, float s1) {
#pragma clang fp contract(off)
    int tid = blockIdx.x * 256 + threadIdx.x;
    int row = tid >> 2, h = tid & 3;
    int n = row & (NPT - 1), s = row >> 12, b = s >> 1, e = s & 1;
    int base4 = b * 8192 + e, srow = s * NPT;
    float se = (s & 1) ? s1 : s0;
    float4 t4 = tgt[base4 + n * 2];
    float3 tj = cellpos(t4, n);
    bool tv = t4.w > 0.5f;
    if (h == 0) {
        out[O_TPOS + row * 3 + 0] = tj.x;
        out[O_TPOS + row * 3 + 1] = tj.y;
        out[O_TPOS + row * 3 + 2] = tj.z;
        out[O_MASKT + row] = tv ? 1.0f : 0.0f;
    }
    if (!tv) {   // quad-uniform early out (all-inf row -> masks 0, idx 0)
        if (h == 0) {
            out[O_TPT + row] = 0.0f; out[O_TPTN + row] = 0.0f;
            out[O_TPP + row] = 0.0f; out[O_TPPN + row] = 0.0f;
        }
        return;
    }
    int gx = n >> 7, gy = (n >> 2) & 31;
    unsigned long long bs = ~0ull, bn = ~0ull;
    unsigned as_ = 0, an_ = 0;
    for (int qq = 0; qq < 7; ++qq) {
        int q = qq * 4 + h;                      // h=0 gets 7 pairs, others 6
        if (q > 24) continue;
        int nx = gx + q / 5 - 2, ny = gy + q % 5 - 2;
        if ((unsigned)nx > 31u || (unsigned)ny > 31u) continue;
        int nb = nx * 128 + ny * 4;
#pragma unroll
        for (int nz = 0; nz < 4; ++nz) {
            int ni = nb + nz;
            float4 pi = pred[base4 + ni * 2];
            float3 qi = cellpos(pi, ni);
            float d2 = dist2(tj, qi);
            float dist = sqrtf(d2);
            unsigned long long enc =
                ((unsigned long long)__float_as_uint(dist) << 32) | (unsigned)ni;
            if (pi.w > 0.5f) { if (enc < bs) bs = enc; if (d2 < se) as_ = 1u; }
            if (keepu[srow + ni]) { if (enc < bn) bn = enc; if (d2 < se) an_ = 1u; }
        }
    }
    for (int m = 1; m < 4; m <<= 1) {            // combine across the row-quad
        unsigned long long o = shfl_xor_u64(bs, m); if (o < bs) bs = o;
        o = shfl_xor_u64(bn, m); if (o < bn) bn = o;
        as_ |= __shfl_xor(as_, m);
        an_ |= __shfl_xor(an_, m);
    }
    if (h == 0) {
        out[O_TPT + row]  = as_ ? 1.0f : 0.0f;
        out[O_TPTN + row] = an_ ? 1.0f : 0.0f;
        // empty best -> hi word 0xFFFFFFFF = NaN -> compare false -> fallback
        bool acc_s = __uint_as_float((unsigned)(bs >> 32)) < GUARD;
        bool acc_n = __uint_as_float((unsigned)(bn >> 32)) < GUARD;
        if (acc_s) out[O_TPP + row]  = (float)(unsigned)(bs & 0xffffffffull);
        if (acc_n) out[O_TPPN + row] = (float)(unsigned)(bn & 0xffffffffull);
        if (!acc_s || !acc_n) list[atomicAdd(cnt, 1u)] = (unsigned)row;
    }
}

// ---------------------------------------------------------------------------
// K4: exact full-row fallback (one block per listed row; C is ~0 in practice).
// Writes final TPP/TPPN directly (identical to p1's value when p1 accepted).
__global__ void __launch_bounds__(256) k_match2(const float4* __restrict__ pred,
                                                const float4* __restrict__ tgt,
                                                const unsigned char* __restrict__ keepu,
                                                const unsigned* __restrict__ list,
                                                const unsigned* __restrict__ cnt,
                                                float* __restrict__ out) {
#pragma clang fp contract(off)
    __shared__ unsigned long long rs[4], rn[4];
    unsigned C = *cnt;
    for (unsigned r = blockIdx.x; r < C; r += gridDim.x) {
        int row = (int)list[r];
        int n = row & (NPT - 1), s = row >> 12, b = s >> 1, e = s & 1;
        int base4 = b * 8192 + e, srow = s * NPT;
        float4 t4 = tgt[base4 + n * 2];
        float3 tj = cellpos(t4, n);
        unsigned long long bs = ~0ull, bn = ~0ull;
        for (int k = (int)threadIdx.x; k < NPT; k += 256) {
            float4 pi = pred[base4 + k * 2];
            float3 qi = cellpos(pi, k);
            float d2 = dist2(tj, qi);
            float dist = sqrtf(d2);
            unsigned long long enc =
                ((unsigned long long)__float_as_uint(dist) << 32) | (unsigned)k;
            if (pi.w > 0.5f && enc < bs) bs = enc;
            if (keepu[srow + k] && enc < bn) bn = enc;
        }
        for (int m = 32; m; m >>= 1) {
            unsigned long long o = shfl_down_u64(bs, m); if (o < bs) bs = o;
            o = shfl_down_u64(bn, m); if (o < bn) bn = o;
        }
        int w = (int)(threadIdx.x >> 6);
        if ((threadIdx.x & 63) == 0) { rs[w] = bs; rn[w] = bn; }
        __syncthreads();
        if (threadIdx.x == 0) {
            for (int i = 1; i < 4; ++i) {
                if (rs[i] < bs) bs = rs[i];
                if (rn[i] < bn) bn = rn[i];
            }
            unsigned is_ = (bs == ~0ull) ? 0u : (unsigned)(bs & 0xffffffffull);
            unsigned in_ = (bn == ~0ull) ? 0u : (unsigned)(bn & 0xffffffffull);
            out[O_TPP + row]  = (float)is_;
            out[O_TPPN + row] = (float)in_;
        }
        __syncthreads();
    }
}

// ---------------------------------------------------------------------------
// host: smallest f with sqrtf(f) >= t, so (d2 < f) <=> (sqrtf(d2) < t) bit-exactly.
static float sq_boundary(float t) {
    float f = (float)((double)t * (double)t);
    while (sqrtf(f) >= t) f = nextafterf(f, 0.0f);
    while (sqrtf(f) < t)  f = nextafterf(f, __builtin_inff());
    return f;
}

extern "C" void kernel_launch(void* const* d_in, const int* in_sizes, int n_in,
                              void* d_out, int out_size, void* d_ws, size_t ws_size,
                              hipStream_t stream) {
    (void)in_sizes; (void)n_in; (void)out_size; (void)ws_size;
    const float4* pred = (const float4*)d_in[0];
    const float4* tgt  = (const float4*)d_in[1];
    float* out = (float*)d_out;
    char* ws = (char*)d_ws;

    unsigned char* restru = (unsigned char*)(ws + W_RESTR);
    unsigned char* keepu  = (unsigned char*)(ws + W_KEEP);
    unsigned* cnt  = (unsigned*)(ws + W_CNT);
    unsigned* list = (unsigned*)(ws + W_LIST);

    float s0 = sq_boundary(0.74f);    // ELE_D[0]
    float s1 = sq_boundary(0.528f);   // ELE_D[1]

    k_restrain<<<dim3(128), dim3(256), 0, stream>>>(pred, out, restru, cnt, s0, s1);
    k_suppress<<<dim3(128), dim3(256), 0, stream>>>(pred, restru, out, keepu, s0, s1);
    k_match1 <<<dim3(256), dim3(256), 0, stream>>>(pred, tgt, keepu, out, list, cnt, s0, s1);
    k_match2 <<<dim3(128), dim3(256), 0, stream>>>(pred, tgt, keepu, list, cnt, out);
}